// Round 2
// baseline (2543.068 us; speedup 1.0000x reference)
//
#include <hip/hip_runtime.h>

// Swin block, MI355X gfx950. Global I/O fp32 (per reference); internal GEMMs
// bf16 via v_mfma_f32_16x16x32_bf16 with fp32 accumulation.
// Pipeline per batch-slice:
//   K0 cvt_weights : qkv_w/proj_w/w1/w2 fp32 -> bf16 in ws (once per call)
//   K1 attn_fused  : x -> x2 = x + proj(attn(LN1(x))), xln = LN2(x2)
//                    [per-head software pipeline QKV(h) || attn(h-1);
//                     26.6 KB LDS -> high occupancy; 7 barriers]
//   K2 mlp_fused   : out = x2 + gelu(xln@w1^T+b1)@w2^T + b2
//                    [64-token tile; mh chunk wave-private in LDS; 1 barrier]

typedef short s8v __attribute__((ext_vector_type(8)));
typedef float f4v __attribute__((ext_vector_type(4)));
typedef unsigned short u16;

static __device__ __forceinline__ float b2f(u16 u) {
    unsigned int x = ((unsigned int)u) << 16;
    return __builtin_bit_cast(float, x);
}
static __device__ __forceinline__ u16 f2b(float f) {
    unsigned int u = __builtin_bit_cast(unsigned int, f);
    u = (u + 0x7FFF + ((u >> 16) & 1)) >> 16;   // RNE
    return (u16)u;
}
static __device__ __forceinline__ f4v mfma16(s8v a, s8v b, f4v c) {
    return __builtin_amdgcn_mfma_f32_16x16x32_bf16(a, b, c, 0, 0, 0);
}

// XOR swizzle: flip elem-index bits 3..5 with (row&7). Bijective for all tiles
// used here (verified per-stride); 8-elem chunks stay contiguous/16B-aligned;
// spreads column reads of row-major tiles over >=8 banks (<=2-way, free).
#define SWZ(r, e) ((e) ^ (((r) & 7) << 3))

// sizes (elems) of the 4 weight matrices and their bf16 ws offsets
#define SZ_QKV  110592   // 576 x 192
#define SZ_PROJ  36864   // 192 x 192
#define SZ_W1   147456   // 768 x 192
#define SZ_W2   147456   // 192 x 768
#define OFF_PROJ (SZ_QKV)
#define OFF_W1   (SZ_QKV + SZ_PROJ)
#define OFF_W2   (SZ_QKV + SZ_PROJ + SZ_W1)
#define W_TOTAL  (SZ_QKV + SZ_PROJ + SZ_W1 + SZ_W2)   // 442368

// =============== K0: weight fp32 -> bf16 =====================================
__global__ __launch_bounds__(256) void cvt_weights(
    const float* __restrict__ qkv_w, const float* __restrict__ proj_w,
    const float* __restrict__ w1, const float* __restrict__ w2,
    u16* __restrict__ dst)
{
    int i4 = (blockIdx.x * 256 + threadIdx.x) * 4;
    const float* src; int off;
    if (i4 < OFF_PROJ)     { src = qkv_w; off = i4; }
    else if (i4 < OFF_W1)  { src = proj_w; off = i4 - OFF_PROJ; }
    else if (i4 < OFF_W2)  { src = w1; off = i4 - OFF_W1; }
    else                   { src = w2; off = i4 - OFF_W2; }
    float4 v = *(const float4*)(src + off);
    ushort4 o;
    o.x = f2b(v.x); o.y = f2b(v.y); o.z = f2b(v.z); o.w = f2b(v.w);
    *(ushort4*)(dst + i4) = o;
}

// ---- attn helpers -----------------------------------------------------------
// QKV mini-GEMM for head h: 64 tokens x [q32|k32|v32], K=192.
// Writes l2norm'd k -> kb [64][32] swz, v -> vb [32][64] swz (transposed),
// l2norm'd q -> wave scratch, returns the wave's q A-frag.
static __device__ __forceinline__ void qkv_head(
    int h, const s8v* af, const u16* __restrict__ Wqkv,
    const float* __restrict__ bqkv, u16* kb, u16* vb, u16* qw,
    s8v& aqOut, int wv, int lr, int lq)
{
    f4v acc[6] = {};
#pragma unroll
    for (int k = 0; k < 6; k++) {
#pragma unroll
        for (int n = 0; n < 6; n++) {
            int wr = (n < 2) ? (32 * h + 16 * n + lr)
                   : (n < 4) ? (192 + 32 * h + 16 * (n - 2) + lr)
                             : (384 + 32 * h + 16 * (n - 4) + lr);
            s8v bf = *(const s8v*)&Wqkv[(size_t)wr * 192 + 32 * k + lq * 8];
            acc[n] = mfma16(af[k], bf, acc[n]);
        }
    }
    float bq0 = bqkv[32 * h + lr],       bq1 = bqkv[32 * h + 16 + lr];
    float bk0 = bqkv[192 + 32 * h + lr], bk1 = bqkv[192 + 32 * h + 16 + lr];
    float bv0 = bqkv[384 + 32 * h + lr], bv1 = bqkv[384 + 32 * h + 16 + lr];
#pragma unroll
    for (int reg = 0; reg < 4; reg++) {
        int row = 16 * wv + lq * 4 + reg;
        float q0 = acc[0][reg] + bq0, q1 = acc[1][reg] + bq1;
        float ss = q0 * q0 + q1 * q1;
#pragma unroll
        for (int m = 1; m < 16; m <<= 1) ss += __shfl_xor(ss, m);
        float inv = 1.0f / fmaxf(sqrtf(ss), 1e-12f);
        qw[(lq * 4 + reg) * 40 + lr]      = f2b(q0 * inv);
        qw[(lq * 4 + reg) * 40 + 16 + lr] = f2b(q1 * inv);

        float k0v = acc[2][reg] + bk0, k1v = acc[3][reg] + bk1;
        ss = k0v * k0v + k1v * k1v;
#pragma unroll
        for (int m = 1; m < 16; m <<= 1) ss += __shfl_xor(ss, m);
        inv = 1.0f / fmaxf(sqrtf(ss), 1e-12f);
        kb[SWZ(row, row * 32 + lr)]      = f2b(k0v * inv);
        kb[SWZ(row, row * 32 + 16 + lr)] = f2b(k1v * inv);

        vb[SWZ(lr, lr * 64 + row)]             = f2b(acc[4][reg] + bv0);
        vb[SWZ(16 + lr, (16 + lr) * 64 + row)] = f2b(acc[5][reg] + bv1);
    }
    aqOut = *(const s8v*)&qw[lr * 40 + lq * 8];
}

// S = q k^T -> softmax/clip -> O = P V -> accumulate proj into acc2.
static __device__ __forceinline__ void attn_head(
    int h, s8v aq, const u16* kb, const u16* vb, u16* pw,
    f4v* acc2, const u16* __restrict__ Wproj, int wv, int lr, int lq)
{
    f4v accS[4] = {};
#pragma unroll
    for (int j = 0; j < 4; j++) {
        int kr = 16 * j + lr;
        s8v bk = *(const s8v*)&kb[SWZ(kr, kr * 32 + lq * 8)];
        accS[j] = mfma16(aq, bk, accS[j]);
    }
    const float scale = 0.17677669529663687f;   // 32^-0.5
    float p[4][4];
#pragma unroll
    for (int reg = 0; reg < 4; reg++) {
        float v0 = accS[0][reg] * scale, v1 = accS[1][reg] * scale;
        float v2 = accS[2][reg] * scale, v3 = accS[3][reg] * scale;
        float mx = fmaxf(fmaxf(v0, v1), fmaxf(v2, v3));
#pragma unroll
        for (int m = 1; m < 16; m <<= 1) mx = fmaxf(mx, __shfl_xor(mx, m));
        float e0 = __expf(v0 - mx), e1 = __expf(v1 - mx);
        float e2 = __expf(v2 - mx), e3 = __expf(v3 - mx);
        float sum = e0 + e1 + e2 + e3;
#pragma unroll
        for (int m = 1; m < 16; m <<= 1) sum += __shfl_xor(sum, m);
        float is = 1.0f / sum;
        p[0][reg] = fminf(fmaxf(e0 * is, 1e-6f), 1.0f);
        p[1][reg] = fminf(fmaxf(e1 * is, 1e-6f), 1.0f);
        p[2][reg] = fminf(fmaxf(e2 * is, 1e-6f), 1.0f);
        p[3][reg] = fminf(fmaxf(e3 * is, 1e-6f), 1.0f);
    }
    f4v accO[2] = {};
#pragma unroll
    for (int reg = 0; reg < 4; reg++) {
        pw[(lq * 4 + reg) * 40 + lr]      = f2b(p[0][reg]);
        pw[(lq * 4 + reg) * 40 + 16 + lr] = f2b(p[1][reg]);
    }
    {
        s8v ap = *(const s8v*)&pw[lr * 40 + lq * 8];
#pragma unroll
        for (int n = 0; n < 2; n++) {
            int d = 16 * n + lr;
            s8v bvf = *(const s8v*)&vb[SWZ(d, d * 64 + lq * 8)];
            accO[n] = mfma16(ap, bvf, accO[n]);
        }
    }
#pragma unroll
    for (int reg = 0; reg < 4; reg++) {
        pw[(lq * 4 + reg) * 40 + lr]      = f2b(p[2][reg]);
        pw[(lq * 4 + reg) * 40 + 16 + lr] = f2b(p[3][reg]);
    }
    {
        s8v ap = *(const s8v*)&pw[lr * 40 + lq * 8];
#pragma unroll
        for (int n = 0; n < 2; n++) {
            int d = 16 * n + lr;
            s8v bvf = *(const s8v*)&vb[SWZ(d, d * 64 + 32 + lq * 8)];
            accO[n] = mfma16(ap, bvf, accO[n]);
        }
    }
    // O transpose via scratch; accumulate proj
#pragma unroll
    for (int n = 0; n < 2; n++)
#pragma unroll
        for (int reg = 0; reg < 4; reg++)
            pw[(lq * 4 + reg) * 40 + 16 * n + lr] = f2b(accO[n][reg]);
    s8v apj = *(const s8v*)&pw[lr * 40 + lq * 8];
#pragma unroll
    for (int n = 0; n < 12; n++) {
        s8v bpj = *(const s8v*)&Wproj[(size_t)(16 * n + lr) * 192 + 32 * h + lq * 8];
        acc2[n] = mfma16(apj, bpj, acc2[n]);
    }
}

// =============== K1: fused LN1 + QKV + window-attention + proj + resid + LN2 =
// LDS (elems): phase1 hs[0,12288) = 64x192 swz LN1 tokens (dead after af load)
//              phase2 kb0[0,2048) kb1[2048,4096) vb0[4096,6144) vb1[6144,8192)
//                     qscr[8192,10752) pscr[10752,13312)   (aliases hs)
__global__ __launch_bounds__(256, 4) void attn_fused(
    const float* __restrict__ x, const u16* __restrict__ Wqkv,
    const float* __restrict__ bqkv, const u16* __restrict__ Wproj,
    const float* __restrict__ bproj, const float* __restrict__ g1,
    const float* __restrict__ bn1, const float* __restrict__ g2,
    const float* __restrict__ bn2, u16* __restrict__ x2,
    u16* __restrict__ xln)
{
    __shared__ __align__(16) u16 lds[13312];   // 26624 B
    u16* hs   = lds;
    u16* qscr = lds + 8192;
    u16* pscr = lds + 10752;

    const int tid = threadIdx.x;
    const int wv = tid >> 6, lane = tid & 63;
    const int lr = lane & 15, lq = lane >> 4;
    const int wloc = blockIdx.x;
    const int bb = wloc >> 8, wh = (wloc >> 4) & 15, ww = wloc & 15;
    u16* qw = qscr + wv * 640;
    u16* pw = pscr + wv * 640;

    // ---- LN1 stage (single pass; x kept in registers) ----
    {
        int tk = tid >> 2, q4 = tid & 3;
        int gh = (wh * 8 + (tk >> 3) + 4) & 127;
        int gw = (ww * 8 + (tk & 7) + 4) & 127;
        const float* xr = x + (((size_t)bb * 128 + gh) * 128 + gw) * 192 + q4 * 48;
        float4 xv[12];
        float s = 0.f, sq = 0.f;
#pragma unroll
        for (int i = 0; i < 12; i++) {
            xv[i] = *(const float4*)(xr + i * 4);
            s += xv[i].x + xv[i].y + xv[i].z + xv[i].w;
            sq += xv[i].x * xv[i].x + xv[i].y * xv[i].y
                + xv[i].z * xv[i].z + xv[i].w * xv[i].w;
        }
        s += __shfl_xor(s, 1); sq += __shfl_xor(sq, 1);
        s += __shfl_xor(s, 2); sq += __shfl_xor(sq, 2);
        float mean = s * (1.0f / 192.0f);
        float var = sq * (1.0f / 192.0f) - mean * mean;
        float rstd = 1.0f / sqrtf(var + 1e-5f);
#pragma unroll
        for (int i = 0; i < 12; i += 2) {
            int c0 = q4 * 48 + i * 4;
            float4 ga  = *(const float4*)(g1 + c0);
            float4 gb  = *(const float4*)(g1 + c0 + 4);
            float4 ba  = *(const float4*)(bn1 + c0);
            float4 bbv = *(const float4*)(bn1 + c0 + 4);
            s8v ov;
            ov[0] = (short)f2b((xv[i].x - mean) * rstd * ga.x + ba.x);
            ov[1] = (short)f2b((xv[i].y - mean) * rstd * ga.y + ba.y);
            ov[2] = (short)f2b((xv[i].z - mean) * rstd * ga.z + ba.z);
            ov[3] = (short)f2b((xv[i].w - mean) * rstd * ga.w + ba.w);
            ov[4] = (short)f2b((xv[i + 1].x - mean) * rstd * gb.x + bbv.x);
            ov[5] = (short)f2b((xv[i + 1].y - mean) * rstd * gb.y + bbv.y);
            ov[6] = (short)f2b((xv[i + 1].z - mean) * rstd * gb.z + bbv.z);
            ov[7] = (short)f2b((xv[i + 1].w - mean) * rstd * gb.w + bbv.w);
            *(s8v*)&hs[SWZ(tk, tk * 192 + c0)] = ov;
        }
    }
    // wave-local A-frag load (each wave reads only rows it wrote)
    const int trow = 16 * wv + lr;
    s8v af[6];
#pragma unroll
    for (int k = 0; k < 6; k++)
        af[k] = *(const s8v*)&hs[SWZ(trow, trow * 192 + 32 * k + lq * 8)];
    __syncthreads();                 // B1: hs readers done -> region reusable

    // ---- per-head pipeline: QKV(h) overlaps attn(h-1); 1 barrier/head ----
    f4v acc2[12] = {};
    s8v aqv[6];
#pragma unroll
    for (int h = 0; h < 6; h++) {
        u16* kb = lds + ((h & 1) << 11);
        u16* vb = lds + 4096 + ((h & 1) << 11);
        qkv_head(h, af, Wqkv, bqkv, kb, vb, qw, aqv[h], wv, lr, lq);
        if (h > 0) {
            u16* kbp = lds + (((h - 1) & 1) << 11);
            u16* vbp = lds + 4096 + (((h - 1) & 1) << 11);
            attn_head(h - 1, aqv[h - 1], kbp, vbp, pw, acc2, Wproj, wv, lr, lq);
        }
        __syncthreads();             // kb/vb of head h published to all waves
    }
    attn_head(5, aqv[5], lds + 2048, lds + 4096 + 2048, pw, acc2, Wproj, wv, lr, lq);

    // ---- epilogue: x2 = proj + bias + x (roll(+4) scatter); fused LN2 ----
    float bpv[12], g2v[12], b2v[12];
#pragma unroll
    for (int n = 0; n < 12; n++) {
        int col = 16 * n + lr;
        bpv[n] = bproj[col]; g2v[n] = g2[col]; b2v[n] = bn2[col];
    }
#pragma unroll
    for (int reg = 0; reg < 4; reg++) {
        int tk = 16 * wv + lq * 4 + reg;
        int gh = (wh * 8 + (tk >> 3) + 4) & 127;
        int gw = (ww * 8 + (tk & 7) + 4) & 127;
        size_t base = (((size_t)bb * 128 + gh) * 128 + gw) * 192;
        float vv[12];
        float s = 0.f, sq = 0.f;
#pragma unroll
        for (int n = 0; n < 12; n++) {
            float v = acc2[n][reg] + bpv[n] + x[base + 16 * n + lr];
            vv[n] = v; s += v; sq += v * v;
        }
        s += __shfl_xor(s, 1); sq += __shfl_xor(sq, 1);
        s += __shfl_xor(s, 2); sq += __shfl_xor(sq, 2);
        s += __shfl_xor(s, 4); sq += __shfl_xor(sq, 4);
        s += __shfl_xor(s, 8); sq += __shfl_xor(sq, 8);
        float mean = s * (1.0f / 192.0f);
        float var = sq * (1.0f / 192.0f) - mean * mean;
        float rstd = 1.0f / sqrtf(var + 1e-5f);
#pragma unroll
        for (int n = 0; n < 12; n++) {
            size_t idx = base + 16 * n + lr;
            x2[idx]  = f2b(vv[n]);
            xln[idx] = f2b((vv[n] - mean) * rstd * g2v[n] + b2v[n]);
        }
    }
}

// =============== K2: fused MLP: out = x2 + gelu(xln@W1^T+b1)@W2^T + b2 =======
// 64-token tile; 4 chunks of 192 hidden cols; mh chunk lives in wave-private
// LDS rows (each wave reads only rows it wrote -> no barriers in chunk loop).
__global__ __launch_bounds__(256, 3) void mlp_fused(
    const u16* __restrict__ xln, const u16* __restrict__ x2,
    const u16* __restrict__ W1, const float* __restrict__ B1,
    const u16* __restrict__ W2, const float* __restrict__ B2,
    float* __restrict__ out)
{
    __shared__ __align__(16) u16 lds[24576];   // 49152 B: As + Ms
    u16* As = lds;            // 64 x 192 swz (xln tile)
    u16* Ms = lds + 12288;    // 64 x 192 swz (mh chunk, wave-private rows)
    const int tid = threadIdx.x;
    const int wv = tid >> 6, lane = tid & 63;
    const int lr = lane & 15, lq = lane >> 4;
    const size_t m0 = (size_t)blockIdx.x * 64;

    {   // stage xln tile (coalesced)
        int r = tid >> 2, q4 = tid & 3;
        const u16* xr = xln + (m0 + r) * 192 + q4 * 48;
        int ebase = r * 192 + q4 * 48;
#pragma unroll
        for (int i = 0; i < 6; i++)
            *(s8v*)&As[SWZ(r, ebase + i * 8)] = *(const s8v*)(xr + i * 8);
    }
    __syncthreads();

    f4v facc[12] = {};
    const int arow = 16 * wv + lr;
#pragma unroll
    for (int c = 0; c < 4; c++) {
        // GEMM1: g = xln @ W1_c^T  (M=16/wave, N=192, K=192)
        f4v g[12] = {};
#pragma unroll
        for (int k = 0; k < 6; k++) {
            s8v a = *(const s8v*)&As[SWZ(arow, arow * 192 + 32 * k + lq * 8)];
#pragma unroll
            for (int n = 0; n < 12; n++) {
                s8v bf = *(const s8v*)&W1[(size_t)(c * 192 + 16 * n + lr) * 192 + 32 * k + lq * 8];
                g[n] = mfma16(a, bf, g[n]);
            }
        }
        // bias + exact gelu -> Ms (wave-private rows)
#pragma unroll
        for (int n = 0; n < 12; n++) {
            int col = 16 * n + lr;
            float bb = B1[c * 192 + col];
#pragma unroll
            for (int reg = 0; reg < 4; reg++) {
                int row = 16 * wv + lq * 4 + reg;
                float v = g[n][reg] + bb;
                v = 0.5f * v * (1.0f + erff(v * 0.70710678118654752f));
                Ms[SWZ(row, row * 192 + col)] = f2b(v);
            }
        }
        // GEMM2: facc += mh_c @ W2_c^T  (in-wave LDS ordering, no barrier)
#pragma unroll
        for (int k = 0; k < 6; k++) {
            s8v a2 = *(const s8v*)&Ms[SWZ(arow, arow * 192 + 32 * k + lq * 8)];
#pragma unroll
            for (int n = 0; n < 12; n++) {
                s8v bf = *(const s8v*)&W2[(size_t)(16 * n + lr) * 768 + c * 192 + 32 * k + lq * 8];
                facc[n] = mfma16(a2, bf, facc[n]);
            }
        }
    }

    // epilogue: + b2 + residual x2 (bf16), fp32 out
#pragma unroll
    for (int n = 0; n < 12; n++) {
        int col = 16 * n + lr;
        float bb = B2[col];
#pragma unroll
        for (int reg = 0; reg < 4; reg++) {
            size_t row = m0 + 16 * wv + lq * 4 + reg;
            out[row * 192 + col] = facc[n][reg] + bb + b2f(x2[row * 192 + col]);
        }
    }
}

// ---------------- driver -----------------------------------------------------
extern "C" void kernel_launch(void* const* d_in, const int* in_sizes, int n_in,
                              void* d_out, int out_size, void* d_ws, size_t ws_size,
                              hipStream_t stream) {
    const float* x      = (const float*)d_in[0];
    const float* qkv_w  = (const float*)d_in[1];
    const float* qkv_b  = (const float*)d_in[2];
    const float* proj_w = (const float*)d_in[3];
    const float* proj_b = (const float*)d_in[4];
    const float* n1_g   = (const float*)d_in[5];
    const float* n1_b   = (const float*)d_in[6];
    const float* n2_g   = (const float*)d_in[7];
    const float* n2_b   = (const float*)d_in[8];
    const float* w1     = (const float*)d_in[9];
    const float* b1     = (const float*)d_in[10];
    const float* w2     = (const float*)d_in[11];
    const float* b2     = (const float*)d_in[12];
    float* out = (float*)d_out;

    u16* wsu = (u16*)d_ws;
    u16* wQ  = wsu;
    u16* wP  = wsu + OFF_PROJ;
    u16* wW1 = wsu + OFF_W1;
    u16* wW2 = wsu + OFF_W2;
    char* dataBase = (char*)d_ws + (1 << 20);
    size_t avail = (ws_size > (1 << 20)) ? ws_size - (1 << 20) : 0;

    dim3 blk(256);
    cvt_weights<<<W_TOTAL / 1024, blk, 0, stream>>>(qkv_w, proj_w, w1, w2, wsu);

    // largest Bs with x2 + xln (Ts x 192 each, bf16) resident in ws
    const size_t perTok = (size_t)(192 + 192) * 2;
    int Bs = 16;
    while (Bs > 1 && (size_t)Bs * 16384 * perTok > avail) Bs >>= 1;
    const int nslice = 16 / Bs;
    const size_t stok = (size_t)Bs * 16384;
    u16* x2buf  = (u16*)dataBase;
    u16* xlnbuf = x2buf + stok * 192;

    for (int s = 0; s < nslice; s++) {
        const float* xs = x + (size_t)s * stok * 192;
        float* outs = out + (size_t)s * stok * 192;
        attn_fused<<<Bs * 256, blk, 0, stream>>>(xs, wQ, qkv_b, wP, proj_b,
                                                 n1_g, n1_b, n2_g, n2_b,
                                                 x2buf, xlnbuf);
        mlp_fused<<<Bs * 256, blk, 0, stream>>>(xlnbuf, x2buf, wW1, b1,
                                                wW2, b2, outs);
    }
}

// Round 3
// 1854.525 us; speedup vs baseline: 1.3713x; 1.3713x over previous
//
#include <hip/hip_runtime.h>

// Swin block, MI355X gfx950. Global I/O fp32 (per reference); internal GEMMs
// bf16 via v_mfma_f32_16x16x32_bf16 with fp32 accumulation.
// Pipeline per batch-slice:
//   K0 cvt_weights : qkv_w/proj_w/w1/w2 fp32 -> bf16 in ws (once per call)
//   K1 attn_fused  : x -> x2 = x + proj(attn(LN1(x))), xln = LN2(x2)
//                    [round-1 version, verbatim: 3 barriers, 54.3 KB LDS]
//   K2 mlp_fused   : out = x2 + gelu(xln@w1^T+b1)@w2^T + b2
//                    [spill-proof: wave M=16 (facc=48 VGPR), W1 staged in LDS
//                     64 hidden rows/step, W2 frags from L2, mh wave-private]

typedef short s8v __attribute__((ext_vector_type(8)));
typedef float f4v __attribute__((ext_vector_type(4)));
typedef unsigned short u16;

static __device__ __forceinline__ float b2f(u16 u) {
    unsigned int x = ((unsigned int)u) << 16;
    return __builtin_bit_cast(float, x);
}
static __device__ __forceinline__ u16 f2b(float f) {
    unsigned int u = __builtin_bit_cast(unsigned int, f);
    u = (u + 0x7FFF + ((u >> 16) & 1)) >> 16;   // RNE
    return (u16)u;
}
static __device__ __forceinline__ f4v mfma16(s8v a, s8v b, f4v c) {
    return __builtin_amdgcn_mfma_f32_16x16x32_bf16(a, b, c, 0, 0, 0);
}

// Inline exact-enough gelu (erf via Abramowitz-Stegun 7.1.26, |err|<1.5e-7).
// No libm call -> no ABI spill risk in the hot loop.
static __device__ __forceinline__ float gelu_f(float v) {
    float z = v * 0.70710678118654752f;
    float az = fabsf(z);
    float t = 1.0f / (1.0f + 0.3275911f * az);
    float poly = t * (0.254829592f + t * (-0.284496736f + t * (1.421413741f
               + t * (-1.453152027f + t * 1.061405429f))));
    float erfv = 1.0f - poly * __expf(-az * az);
    erfv = __builtin_copysignf(erfv, z);
    return 0.5f * v * (1.0f + erfv);
}

// XOR swizzle: flip elem-index bits 3..5 with (row&7). Bijective for all tiles
// used here; 8-elem chunks stay contiguous/16B-aligned; spreads column reads
// of row-major tiles over >=8 banks (<=2-way, free).
#define SWZ(r, e) ((e) ^ (((r) & 7) << 3))

// sizes (elems) of the 4 weight matrices and their bf16 ws offsets
#define SZ_QKV  110592   // 576 x 192
#define SZ_PROJ  36864   // 192 x 192
#define SZ_W1   147456   // 768 x 192
#define SZ_W2   147456   // 192 x 768
#define OFF_PROJ (SZ_QKV)
#define OFF_W1   (SZ_QKV + SZ_PROJ)
#define OFF_W2   (SZ_QKV + SZ_PROJ + SZ_W1)
#define W_TOTAL  (SZ_QKV + SZ_PROJ + SZ_W1 + SZ_W2)   // 442368

// =============== K0: weight fp32 -> bf16 =====================================
__global__ __launch_bounds__(256) void cvt_weights(
    const float* __restrict__ qkv_w, const float* __restrict__ proj_w,
    const float* __restrict__ w1, const float* __restrict__ w2,
    u16* __restrict__ dst)
{
    int i4 = (blockIdx.x * 256 + threadIdx.x) * 4;
    const float* src; int off;
    if (i4 < OFF_PROJ)     { src = qkv_w; off = i4; }
    else if (i4 < OFF_W1)  { src = proj_w; off = i4 - OFF_PROJ; }
    else if (i4 < OFF_W2)  { src = w1; off = i4 - OFF_W1; }
    else                   { src = w2; off = i4 - OFF_W2; }
    float4 v = *(const float4*)(src + off);
    ushort4 o;
    o.x = f2b(v.x); o.y = f2b(v.y); o.z = f2b(v.z); o.w = f2b(v.w);
    *(ushort4*)(dst + i4) = o;
}

// =============== K1: fused LN1 + QKV + window-attention + proj + resid + LN2 =
// Round-1 version verbatim (measured 671 us, no scratch traffic).
__global__ __launch_bounds__(256, 3) void attn_fused(
    const float* __restrict__ x, const u16* __restrict__ Wqkv,
    const float* __restrict__ bqkv, const u16* __restrict__ Wproj,
    const float* __restrict__ bproj, const float* __restrict__ g1,
    const float* __restrict__ bn1, const float* __restrict__ g2,
    const float* __restrict__ bn2, u16* __restrict__ x2,
    u16* __restrict__ xln)
{
    __shared__ __align__(16) u16 lds[27136];   // 54272 B
    u16* hs   = lds;           // 64 x 192 swz (LN1 tokens); dead after frag load
    u16* ks   = lds;           // ALIASES hs: 64 x 192 swz (l2norm'd k)
    u16* vt   = lds + 12288;   // 192 x 64 swz (v transposed [dim][token])
    u16* pscr = lds + 24576;   // 4 waves x 16 x 40 wave-private scratch

    const int tid = threadIdx.x;
    const int wv = tid >> 6, lane = tid & 63;
    const int lr = lane & 15, lq = lane >> 4;
    const int wloc = blockIdx.x;
    const int bb = wloc >> 8, wh = (wloc >> 4) & 15, ww = wloc & 15;
    u16* pw = pscr + wv * 640;

    // ---- LN1 stage (single pass; x kept in registers) ----
    {
        int tk = tid >> 2, q4 = tid & 3;
        int gh = (wh * 8 + (tk >> 3) + 4) & 127;
        int gw = (ww * 8 + (tk & 7) + 4) & 127;
        const float* xr = x + (((size_t)bb * 128 + gh) * 128 + gw) * 192 + q4 * 48;
        float4 xv[12];
        float s = 0.f, sq = 0.f;
#pragma unroll
        for (int i = 0; i < 12; i++) {
            xv[i] = *(const float4*)(xr + i * 4);
            s += xv[i].x + xv[i].y + xv[i].z + xv[i].w;
            sq += xv[i].x * xv[i].x + xv[i].y * xv[i].y
                + xv[i].z * xv[i].z + xv[i].w * xv[i].w;
        }
        s += __shfl_xor(s, 1); sq += __shfl_xor(sq, 1);
        s += __shfl_xor(s, 2); sq += __shfl_xor(sq, 2);
        float mean = s * (1.0f / 192.0f);
        float var = sq * (1.0f / 192.0f) - mean * mean;
        float rstd = 1.0f / sqrtf(var + 1e-5f);
#pragma unroll
        for (int i = 0; i < 12; i += 2) {
            int c0 = q4 * 48 + i * 4;
            float4 ga  = *(const float4*)(g1 + c0);
            float4 gb  = *(const float4*)(g1 + c0 + 4);
            float4 ba  = *(const float4*)(bn1 + c0);
            float4 bbv = *(const float4*)(bn1 + c0 + 4);
            s8v ov;
            ov[0] = (short)f2b((xv[i].x - mean) * rstd * ga.x + ba.x);
            ov[1] = (short)f2b((xv[i].y - mean) * rstd * ga.y + ba.y);
            ov[2] = (short)f2b((xv[i].z - mean) * rstd * ga.z + ba.z);
            ov[3] = (short)f2b((xv[i].w - mean) * rstd * ga.w + ba.w);
            ov[4] = (short)f2b((xv[i + 1].x - mean) * rstd * gb.x + bbv.x);
            ov[5] = (short)f2b((xv[i + 1].y - mean) * rstd * gb.y + bbv.y);
            ov[6] = (short)f2b((xv[i + 1].z - mean) * rstd * gb.z + bbv.z);
            ov[7] = (short)f2b((xv[i + 1].w - mean) * rstd * gb.w + bbv.w);
            *(s8v*)&hs[SWZ(tk, tk * 192 + c0)] = ov;
        }
    }
    __syncthreads();                       // barrier 1: hs complete

    const int trow = 16 * wv + lr;
    s8v af[6];
#pragma unroll
    for (int k = 0; k < 6; k++)
        af[k] = *(const s8v*)&hs[SWZ(trow, trow * 192 + 32 * k + lq * 8)];
    __syncthreads();                       // barrier 2: hs region free -> ks

    // ---- QKV phase (all 6 heads, no barriers): q->regs, k->ks, v->vt ----
    s8v aq[6];
#pragma unroll
    for (int h = 0; h < 6; h++) {
        f4v acc[6] = {};
#pragma unroll
        for (int k = 0; k < 6; k++) {
#pragma unroll
            for (int n = 0; n < 6; n++) {
                int wr = (n < 2) ? (32 * h + 16 * n + lr)
                       : (n < 4) ? (192 + 32 * h + 16 * (n - 2) + lr)
                                 : (384 + 32 * h + 16 * (n - 4) + lr);
                s8v bf = *(const s8v*)&Wqkv[(size_t)wr * 192 + 32 * k + lq * 8];
                acc[n] = mfma16(af[k], bf, acc[n]);
            }
        }
        float bq0 = bqkv[32 * h + lr],       bq1 = bqkv[32 * h + 16 + lr];
        float bk0 = bqkv[192 + 32 * h + lr], bk1 = bqkv[192 + 32 * h + 16 + lr];
        float bv0 = bqkv[384 + 32 * h + lr], bv1 = bqkv[384 + 32 * h + 16 + lr];
#pragma unroll
        for (int reg = 0; reg < 4; reg++) {
            int row = 16 * wv + lq * 4 + reg;
            float q0 = acc[0][reg] + bq0, q1 = acc[1][reg] + bq1;
            float ss = q0 * q0 + q1 * q1;
#pragma unroll
            for (int m = 1; m < 16; m <<= 1) ss += __shfl_xor(ss, m);
            float inv = 1.0f / fmaxf(sqrtf(ss), 1e-12f);
            pw[(lq * 4 + reg) * 40 + lr]      = f2b(q0 * inv);
            pw[(lq * 4 + reg) * 40 + 16 + lr] = f2b(q1 * inv);

            float k0v = acc[2][reg] + bk0, k1v = acc[3][reg] + bk1;
            ss = k0v * k0v + k1v * k1v;
#pragma unroll
            for (int m = 1; m < 16; m <<= 1) ss += __shfl_xor(ss, m);
            inv = 1.0f / fmaxf(sqrtf(ss), 1e-12f);
            ks[SWZ(row, row * 192 + 32 * h + lr)]      = f2b(k0v * inv);
            ks[SWZ(row, row * 192 + 32 * h + 16 + lr)] = f2b(k1v * inv);

            int d0 = 32 * h + lr, d1 = 32 * h + 16 + lr;
            vt[SWZ(d0, d0 * 64 + row)] = f2b(acc[4][reg] + bv0);
            vt[SWZ(d1, d1 * 64 + row)] = f2b(acc[5][reg] + bv1);
        }
        aq[h] = *(const s8v*)&pw[lr * 40 + lq * 8];   // q A-frag to regs
    }
    __syncthreads();                       // barrier 3: ks/vt published

    // ---- attention loop: ZERO barriers (only wave-private scratch reuse) ----
    f4v acc2[12] = {};
    const float scale = 0.17677669529663687f;   // 32^-0.5
#pragma unroll
    for (int h = 0; h < 6; h++) {
        f4v accS[4] = {};
#pragma unroll
        for (int j = 0; j < 4; j++) {
            int kr = 16 * j + lr;
            s8v bk = *(const s8v*)&ks[SWZ(kr, kr * 192 + 32 * h + lq * 8)];
            accS[j] = mfma16(aq[h], bk, accS[j]);
        }
        float p[4][4];
#pragma unroll
        for (int reg = 0; reg < 4; reg++) {
            float v0 = accS[0][reg] * scale, v1 = accS[1][reg] * scale;
            float v2 = accS[2][reg] * scale, v3 = accS[3][reg] * scale;
            float mx = fmaxf(fmaxf(v0, v1), fmaxf(v2, v3));
#pragma unroll
            for (int m = 1; m < 16; m <<= 1) mx = fmaxf(mx, __shfl_xor(mx, m));
            float e0 = __expf(v0 - mx), e1 = __expf(v1 - mx);
            float e2 = __expf(v2 - mx), e3 = __expf(v3 - mx);
            float sum = e0 + e1 + e2 + e3;
#pragma unroll
            for (int m = 1; m < 16; m <<= 1) sum += __shfl_xor(sum, m);
            float is = 1.0f / sum;
            p[0][reg] = fminf(fmaxf(e0 * is, 1e-6f), 1.0f);
            p[1][reg] = fminf(fmaxf(e1 * is, 1e-6f), 1.0f);
            p[2][reg] = fminf(fmaxf(e2 * is, 1e-6f), 1.0f);
            p[3][reg] = fminf(fmaxf(e3 * is, 1e-6f), 1.0f);
        }
        // P -> bf16 A-frags in two 32-col halves through wave-private scratch
        f4v accO[2] = {};
#pragma unroll
        for (int reg = 0; reg < 4; reg++) {
            pw[(lq * 4 + reg) * 40 + lr]      = f2b(p[0][reg]);
            pw[(lq * 4 + reg) * 40 + 16 + lr] = f2b(p[1][reg]);
        }
        {
            s8v ap0 = *(const s8v*)&pw[lr * 40 + lq * 8];
#pragma unroll
            for (int n = 0; n < 2; n++) {
                int d = 32 * h + 16 * n + lr;
                s8v bvf = *(const s8v*)&vt[SWZ(d, d * 64 + lq * 8)];
                accO[n] = mfma16(ap0, bvf, accO[n]);
            }
        }
#pragma unroll
        for (int reg = 0; reg < 4; reg++) {
            pw[(lq * 4 + reg) * 40 + lr]      = f2b(p[2][reg]);
            pw[(lq * 4 + reg) * 40 + 16 + lr] = f2b(p[3][reg]);
        }
        {
            s8v ap1 = *(const s8v*)&pw[lr * 40 + lq * 8];
#pragma unroll
            for (int n = 0; n < 2; n++) {
                int d = 32 * h + 16 * n + lr;
                s8v bvf = *(const s8v*)&vt[SWZ(d, d * 64 + 32 + lq * 8)];
                accO[n] = mfma16(ap1, bvf, accO[n]);
            }
        }
        // O transpose via scratch; accumulate proj
#pragma unroll
        for (int n = 0; n < 2; n++)
#pragma unroll
            for (int reg = 0; reg < 4; reg++)
                pw[(lq * 4 + reg) * 40 + 16 * n + lr] = f2b(accO[n][reg]);
        s8v apj = *(const s8v*)&pw[lr * 40 + lq * 8];
#pragma unroll
        for (int n = 0; n < 12; n++) {
            s8v bpj = *(const s8v*)&Wproj[(size_t)(16 * n + lr) * 192 + 32 * h + lq * 8];
            acc2[n] = mfma16(apj, bpj, acc2[n]);
        }
    }

    // ---- epilogue: x2 = proj + bias + x (roll(+4) scatter); fused LN2 ----
    float bpv[12], g2v[12], b2v[12];
#pragma unroll
    for (int n = 0; n < 12; n++) {
        int col = 16 * n + lr;
        bpv[n] = bproj[col]; g2v[n] = g2[col]; b2v[n] = bn2[col];
    }
#pragma unroll
    for (int reg = 0; reg < 4; reg++) {
        int tk = 16 * wv + lq * 4 + reg;
        int gh = (wh * 8 + (tk >> 3) + 4) & 127;
        int gw = (ww * 8 + (tk & 7) + 4) & 127;
        size_t base = (((size_t)bb * 128 + gh) * 128 + gw) * 192;
        float vv[12];
        float s = 0.f, sq = 0.f;
#pragma unroll
        for (int n = 0; n < 12; n++) {
            float v = acc2[n][reg] + bpv[n] + x[base + 16 * n + lr];
            vv[n] = v; s += v; sq += v * v;
        }
        s += __shfl_xor(s, 1); sq += __shfl_xor(sq, 1);
        s += __shfl_xor(s, 2); sq += __shfl_xor(sq, 2);
        s += __shfl_xor(s, 4); sq += __shfl_xor(sq, 4);
        s += __shfl_xor(s, 8); sq += __shfl_xor(sq, 8);
        float mean = s * (1.0f / 192.0f);
        float var = sq * (1.0f / 192.0f) - mean * mean;
        float rstd = 1.0f / sqrtf(var + 1e-5f);
#pragma unroll
        for (int n = 0; n < 12; n++) {
            size_t idx = base + 16 * n + lr;
            x2[idx]  = f2b(vv[n]);
            xln[idx] = f2b((vv[n] - mean) * rstd * g2v[n] + b2v[n]);
        }
    }
}

// =============== K2: fused MLP: out = x2 + gelu(xln@W1^T+b1)@W2^T + b2 =======
// Block = 64 tokens, 4 waves x 16 rows. 12 hidden-steps of 64:
//   stage W1[64 x 192] sub-tile in LDS (shared by 4 waves) ->
//   GEMM1 (g[4], 24 MFMA) -> gelu -> Ms wave-private [16][72] ->
//   GEMM2 (facc[12] += Ms @ W2-frag-from-L2, 24 MFMA).
// Register budget: facc 48 + af 24 + g 16 + temps ~= 110 -> no spill.
__global__ __launch_bounds__(256) void mlp_fused(
    const u16* __restrict__ xln, const u16* __restrict__ x2,
    const u16* __restrict__ W1, const float* __restrict__ B1,
    const u16* __restrict__ W2, const float* __restrict__ B2,
    float* __restrict__ out)
{
    __shared__ __align__(16) u16 lds[16896];   // 33792 B -> 4 blocks/CU
    u16* W1s = lds;                            // [64][192] swz
    const int tid = threadIdx.x;
    const int wv = tid >> 6, lane = tid & 63;
    const int lr = lane & 15, lq = lane >> 4;
    u16* Ms = lds + 12288 + wv * 1152;         // [16][72], wave-private
    const size_t m0 = (size_t)blockIdx.x * 64;
    const int trow = 16 * wv + lr;

    // A-frags (this wave's 16 token rows) straight from global; live all kernel
    s8v af[6];
#pragma unroll
    for (int k = 0; k < 6; k++)
        af[k] = *(const s8v*)&xln[(m0 + trow) * 192 + 32 * k + lq * 8];

    f4v facc[12] = {};
    const int sr = tid >> 2, sq4 = tid & 3;    // staging: row, quarter

    for (int st = 0; st < 12; st++) {
        const int h0 = st * 64;                // hidden base of this step
        __syncthreads();                       // all waves done reading W1s
        {
            const u16* wr = W1 + (size_t)(h0 + sr) * 192 + sq4 * 48;
            const int eb = sr * 192 + sq4 * 48;
#pragma unroll
            for (int i = 0; i < 6; i++)
                *(s8v*)&W1s[SWZ(sr, eb + i * 8)] = *(const s8v*)(wr + i * 8);
        }
        __syncthreads();                       // W1s staged

        // GEMM1: g = xln_rows @ W1s^T  (16 x 64, K=192)
        f4v g[4] = {};
#pragma unroll
        for (int k = 0; k < 6; k++) {
#pragma unroll
            for (int n = 0; n < 4; n++) {
                int br = 16 * n + lr;
                s8v bf = *(const s8v*)&W1s[SWZ(br, br * 192 + 32 * k + lq * 8)];
                g[n] = mfma16(af[k], bf, g[n]);
            }
        }
        // bias + gelu -> Ms (wave-private; in-wave LDS ordering, no barrier)
#pragma unroll
        for (int n = 0; n < 4; n++) {
            float bb = B1[h0 + 16 * n + lr];
#pragma unroll
            for (int reg = 0; reg < 4; reg++)
                Ms[(lq * 4 + reg) * 72 + 16 * n + lr] = f2b(gelu_f(g[n][reg] + bb));
        }
        // GEMM2: facc += Ms @ W2_slice^T  (16 x 192, K=64; B frags from L2)
#pragma unroll
        for (int ksl = 0; ksl < 2; ksl++) {
            s8v am = *(const s8v*)&Ms[lr * 72 + ksl * 32 + lq * 8];
#pragma unroll
            for (int n = 0; n < 12; n++) {
                s8v bf = *(const s8v*)&W2[(size_t)(16 * n + lr) * 768 + h0 + ksl * 32 + lq * 8];
                facc[n] = mfma16(am, bf, facc[n]);
            }
        }
    }

    // epilogue: + b2 + residual x2 (bf16), fp32 out
#pragma unroll
    for (int n = 0; n < 12; n++) {
        int col = 16 * n + lr;
        float bb = B2[col];
#pragma unroll
        for (int reg = 0; reg < 4; reg++) {
            size_t row = m0 + 16 * wv + lq * 4 + reg;
            out[row * 192 + col] = facc[n][reg] + bb + b2f(x2[row * 192 + col]);
        }
    }
}

// ---------------- driver -----------------------------------------------------
extern "C" void kernel_launch(void* const* d_in, const int* in_sizes, int n_in,
                              void* d_out, int out_size, void* d_ws, size_t ws_size,
                              hipStream_t stream) {
    const float* x      = (const float*)d_in[0];
    const float* qkv_w  = (const float*)d_in[1];
    const float* qkv_b  = (const float*)d_in[2];
    const float* proj_w = (const float*)d_in[3];
    const float* proj_b = (const float*)d_in[4];
    const float* n1_g   = (const float*)d_in[5];
    const float* n1_b   = (const float*)d_in[6];
    const float* n2_g   = (const float*)d_in[7];
    const float* n2_b   = (const float*)d_in[8];
    const float* w1     = (const float*)d_in[9];
    const float* b1     = (const float*)d_in[10];
    const float* w2     = (const float*)d_in[11];
    const float* b2     = (const float*)d_in[12];
    float* out = (float*)d_out;

    u16* wsu = (u16*)d_ws;
    u16* wQ  = wsu;
    u16* wP  = wsu + OFF_PROJ;
    u16* wW1 = wsu + OFF_W1;
    u16* wW2 = wsu + OFF_W2;
    char* dataBase = (char*)d_ws + (1 << 20);
    size_t avail = (ws_size > (1 << 20)) ? ws_size - (1 << 20) : 0;

    dim3 blk(256);
    cvt_weights<<<W_TOTAL / 1024, blk, 0, stream>>>(qkv_w, proj_w, w1, w2, wsu);

    // largest Bs with x2 + xln (Ts x 192 each, bf16) resident in ws
    const size_t perTok = (size_t)(192 + 192) * 2;
    int Bs = 16;
    while (Bs > 1 && (size_t)Bs * 16384 * perTok > avail) Bs >>= 1;
    const int nslice = 16 / Bs;
    const size_t stok = (size_t)Bs * 16384;
    u16* x2buf  = (u16*)dataBase;
    u16* xlnbuf = x2buf + stok * 192;

    for (int s = 0; s < nslice; s++) {
        const float* xs = x + (size_t)s * stok * 192;
        float* outs = out + (size_t)s * stok * 192;
        attn_fused<<<Bs * 256, blk, 0, stream>>>(xs, wQ, qkv_b, wP, proj_b,
                                                 n1_g, n1_b, n2_g, n2_b,
                                                 x2buf, xlnbuf);
        mlp_fused<<<Bs * 256, blk, 0, stream>>>(xlnbuf, x2buf, wW1, b1,
                                                wW2, b2, outs);
    }
}

// Round 4
// 1531.958 us; speedup vs baseline: 1.6600x; 1.2106x over previous
//
#include <hip/hip_runtime.h>

// Swin block, MI355X gfx950. Global I/O fp32 (per reference); internal GEMMs
// bf16 via v_mfma_f32_16x16x32_bf16 with fp32 accumulation.
// Pipeline per batch-slice (Bs=4 so mh slice ~100MB stays L3-resident):
//   K0 cvt_weights : qkv_w/proj_w/w1/w2 fp32 -> bf16 in ws (once per call)
//   K1 attn_fused  : x -> x2 = x + proj(attn(LN1(x))), xln = LN2(x2)
//                    [round-1 version verbatim: 3 barriers, 54.3 KB LDS]
//   K2a gemm_gelu  : mh = gelu(xln @ w1^T + b1)   [128x128 tile, 64x64/wave]
//   K2b gemm_out   : out = mh @ w2^T + b2 + x2    [256x64 tile, 64x64/wave]

typedef short s8v __attribute__((ext_vector_type(8)));
typedef float f4v __attribute__((ext_vector_type(4)));
typedef unsigned short u16;

static __device__ __forceinline__ float b2f(u16 u) {
    unsigned int x = ((unsigned int)u) << 16;
    return __builtin_bit_cast(float, x);
}
static __device__ __forceinline__ u16 f2b(float f) {
    unsigned int u = __builtin_bit_cast(unsigned int, f);
    u = (u + 0x7FFF + ((u >> 16) & 1)) >> 16;   // RNE
    return (u16)u;
}
static __device__ __forceinline__ f4v mfma16(s8v a, s8v b, f4v c) {
    return __builtin_amdgcn_mfma_f32_16x16x32_bf16(a, b, c, 0, 0, 0);
}

// Inline gelu (erf via Abramowitz-Stegun 7.1.26, |err|<1.5e-7). No libm call.
static __device__ __forceinline__ float gelu_f(float v) {
    float z = v * 0.70710678118654752f;
    float az = fabsf(z);
    float t = 1.0f / (1.0f + 0.3275911f * az);
    float poly = t * (0.254829592f + t * (-0.284496736f + t * (1.421413741f
               + t * (-1.453152027f + t * 1.061405429f))));
    float erfv = 1.0f - poly * __expf(-az * az);
    erfv = __builtin_copysignf(erfv, z);
    return 0.5f * v * (1.0f + erfv);
}

// XOR swizzle for the attention kernel's 192/64-wide tiles (verified free).
#define SWZ(r, e) ((e) ^ (((r) & 7) << 3))

// sizes (elems) of the 4 weight matrices and their bf16 ws offsets
#define SZ_QKV  110592   // 576 x 192
#define SZ_PROJ  36864   // 192 x 192
#define SZ_W1   147456   // 768 x 192
#define SZ_W2   147456   // 192 x 768
#define OFF_PROJ (SZ_QKV)
#define OFF_W1   (SZ_QKV + SZ_PROJ)
#define OFF_W2   (SZ_QKV + SZ_PROJ + SZ_W1)
#define W_TOTAL  (SZ_QKV + SZ_PROJ + SZ_W1 + SZ_W2)   // 442368

// =============== K0: weight fp32 -> bf16 =====================================
__global__ __launch_bounds__(256) void cvt_weights(
    const float* __restrict__ qkv_w, const float* __restrict__ proj_w,
    const float* __restrict__ w1, const float* __restrict__ w2,
    u16* __restrict__ dst)
{
    int i4 = (blockIdx.x * 256 + threadIdx.x) * 4;
    const float* src; int off;
    if (i4 < OFF_PROJ)     { src = qkv_w; off = i4; }
    else if (i4 < OFF_W1)  { src = proj_w; off = i4 - OFF_PROJ; }
    else if (i4 < OFF_W2)  { src = w1; off = i4 - OFF_W1; }
    else                   { src = w2; off = i4 - OFF_W2; }
    float4 v = *(const float4*)(src + off);
    ushort4 o;
    o.x = f2b(v.x); o.y = f2b(v.y); o.z = f2b(v.z); o.w = f2b(v.w);
    *(ushort4*)(dst + i4) = o;
}

// =============== K1: fused LN1 + QKV + window-attention + proj + resid + LN2 =
// Round-1 version verbatim (measured 671 us, no scratch traffic).
__global__ __launch_bounds__(256, 3) void attn_fused(
    const float* __restrict__ x, const u16* __restrict__ Wqkv,
    const float* __restrict__ bqkv, const u16* __restrict__ Wproj,
    const float* __restrict__ bproj, const float* __restrict__ g1,
    const float* __restrict__ bn1, const float* __restrict__ g2,
    const float* __restrict__ bn2, u16* __restrict__ x2,
    u16* __restrict__ xln)
{
    __shared__ __align__(16) u16 lds[27136];   // 54272 B
    u16* hs   = lds;           // 64 x 192 swz (LN1 tokens); dead after frag load
    u16* ks   = lds;           // ALIASES hs: 64 x 192 swz (l2norm'd k)
    u16* vt   = lds + 12288;   // 192 x 64 swz (v transposed [dim][token])
    u16* pscr = lds + 24576;   // 4 waves x 16 x 40 wave-private scratch

    const int tid = threadIdx.x;
    const int wv = tid >> 6, lane = tid & 63;
    const int lr = lane & 15, lq = lane >> 4;
    const int wloc = blockIdx.x;
    const int bb = wloc >> 8, wh = (wloc >> 4) & 15, ww = wloc & 15;
    u16* pw = pscr + wv * 640;

    // ---- LN1 stage (single pass; x kept in registers) ----
    {
        int tk = tid >> 2, q4 = tid & 3;
        int gh = (wh * 8 + (tk >> 3) + 4) & 127;
        int gw = (ww * 8 + (tk & 7) + 4) & 127;
        const float* xr = x + (((size_t)bb * 128 + gh) * 128 + gw) * 192 + q4 * 48;
        float4 xv[12];
        float s = 0.f, sq = 0.f;
#pragma unroll
        for (int i = 0; i < 12; i++) {
            xv[i] = *(const float4*)(xr + i * 4);
            s += xv[i].x + xv[i].y + xv[i].z + xv[i].w;
            sq += xv[i].x * xv[i].x + xv[i].y * xv[i].y
                + xv[i].z * xv[i].z + xv[i].w * xv[i].w;
        }
        s += __shfl_xor(s, 1); sq += __shfl_xor(sq, 1);
        s += __shfl_xor(s, 2); sq += __shfl_xor(sq, 2);
        float mean = s * (1.0f / 192.0f);
        float var = sq * (1.0f / 192.0f) - mean * mean;
        float rstd = 1.0f / sqrtf(var + 1e-5f);
#pragma unroll
        for (int i = 0; i < 12; i += 2) {
            int c0 = q4 * 48 + i * 4;
            float4 ga  = *(const float4*)(g1 + c0);
            float4 gb  = *(const float4*)(g1 + c0 + 4);
            float4 ba  = *(const float4*)(bn1 + c0);
            float4 bbv = *(const float4*)(bn1 + c0 + 4);
            s8v ov;
            ov[0] = (short)f2b((xv[i].x - mean) * rstd * ga.x + ba.x);
            ov[1] = (short)f2b((xv[i].y - mean) * rstd * ga.y + ba.y);
            ov[2] = (short)f2b((xv[i].z - mean) * rstd * ga.z + ba.z);
            ov[3] = (short)f2b((xv[i].w - mean) * rstd * ga.w + ba.w);
            ov[4] = (short)f2b((xv[i + 1].x - mean) * rstd * gb.x + bbv.x);
            ov[5] = (short)f2b((xv[i + 1].y - mean) * rstd * gb.y + bbv.y);
            ov[6] = (short)f2b((xv[i + 1].z - mean) * rstd * gb.z + bbv.z);
            ov[7] = (short)f2b((xv[i + 1].w - mean) * rstd * gb.w + bbv.w);
            *(s8v*)&hs[SWZ(tk, tk * 192 + c0)] = ov;
        }
    }
    __syncthreads();                       // barrier 1: hs complete

    const int trow = 16 * wv + lr;
    s8v af[6];
#pragma unroll
    for (int k = 0; k < 6; k++)
        af[k] = *(const s8v*)&hs[SWZ(trow, trow * 192 + 32 * k + lq * 8)];
    __syncthreads();                       // barrier 2: hs region free -> ks

    // ---- QKV phase (all 6 heads, no barriers): q->regs, k->ks, v->vt ----
    s8v aq[6];
#pragma unroll
    for (int h = 0; h < 6; h++) {
        f4v acc[6] = {};
#pragma unroll
        for (int k = 0; k < 6; k++) {
#pragma unroll
            for (int n = 0; n < 6; n++) {
                int wr = (n < 2) ? (32 * h + 16 * n + lr)
                       : (n < 4) ? (192 + 32 * h + 16 * (n - 2) + lr)
                                 : (384 + 32 * h + 16 * (n - 4) + lr);
                s8v bf = *(const s8v*)&Wqkv[(size_t)wr * 192 + 32 * k + lq * 8];
                acc[n] = mfma16(af[k], bf, acc[n]);
            }
        }
        float bq0 = bqkv[32 * h + lr],       bq1 = bqkv[32 * h + 16 + lr];
        float bk0 = bqkv[192 + 32 * h + lr], bk1 = bqkv[192 + 32 * h + 16 + lr];
        float bv0 = bqkv[384 + 32 * h + lr], bv1 = bqkv[384 + 32 * h + 16 + lr];
#pragma unroll
        for (int reg = 0; reg < 4; reg++) {
            int row = 16 * wv + lq * 4 + reg;
            float q0 = acc[0][reg] + bq0, q1 = acc[1][reg] + bq1;
            float ss = q0 * q0 + q1 * q1;
#pragma unroll
            for (int m = 1; m < 16; m <<= 1) ss += __shfl_xor(ss, m);
            float inv = 1.0f / fmaxf(sqrtf(ss), 1e-12f);
            pw[(lq * 4 + reg) * 40 + lr]      = f2b(q0 * inv);
            pw[(lq * 4 + reg) * 40 + 16 + lr] = f2b(q1 * inv);

            float k0v = acc[2][reg] + bk0, k1v = acc[3][reg] + bk1;
            ss = k0v * k0v + k1v * k1v;
#pragma unroll
            for (int m = 1; m < 16; m <<= 1) ss += __shfl_xor(ss, m);
            inv = 1.0f / fmaxf(sqrtf(ss), 1e-12f);
            ks[SWZ(row, row * 192 + 32 * h + lr)]      = f2b(k0v * inv);
            ks[SWZ(row, row * 192 + 32 * h + 16 + lr)] = f2b(k1v * inv);

            int d0 = 32 * h + lr, d1 = 32 * h + 16 + lr;
            vt[SWZ(d0, d0 * 64 + row)] = f2b(acc[4][reg] + bv0);
            vt[SWZ(d1, d1 * 64 + row)] = f2b(acc[5][reg] + bv1);
        }
        aq[h] = *(const s8v*)&pw[lr * 40 + lq * 8];   // q A-frag to regs
    }
    __syncthreads();                       // barrier 3: ks/vt published

    // ---- attention loop: ZERO barriers (only wave-private scratch reuse) ----
    f4v acc2[12] = {};
    const float scale = 0.17677669529663687f;   // 32^-0.5
#pragma unroll
    for (int h = 0; h < 6; h++) {
        f4v accS[4] = {};
#pragma unroll
        for (int j = 0; j < 4; j++) {
            int kr = 16 * j + lr;
            s8v bk = *(const s8v*)&ks[SWZ(kr, kr * 192 + 32 * h + lq * 8)];
            accS[j] = mfma16(aq[h], bk, accS[j]);
        }
        float p[4][4];
#pragma unroll
        for (int reg = 0; reg < 4; reg++) {
            float v0 = accS[0][reg] * scale, v1 = accS[1][reg] * scale;
            float v2 = accS[2][reg] * scale, v3 = accS[3][reg] * scale;
            float mx = fmaxf(fmaxf(v0, v1), fmaxf(v2, v3));
#pragma unroll
            for (int m = 1; m < 16; m <<= 1) mx = fmaxf(mx, __shfl_xor(mx, m));
            float e0 = __expf(v0 - mx), e1 = __expf(v1 - mx);
            float e2 = __expf(v2 - mx), e3 = __expf(v3 - mx);
            float sum = e0 + e1 + e2 + e3;
#pragma unroll
            for (int m = 1; m < 16; m <<= 1) sum += __shfl_xor(sum, m);
            float is = 1.0f / sum;
            p[0][reg] = fminf(fmaxf(e0 * is, 1e-6f), 1.0f);
            p[1][reg] = fminf(fmaxf(e1 * is, 1e-6f), 1.0f);
            p[2][reg] = fminf(fmaxf(e2 * is, 1e-6f), 1.0f);
            p[3][reg] = fminf(fmaxf(e3 * is, 1e-6f), 1.0f);
        }
        // P -> bf16 A-frags in two 32-col halves through wave-private scratch
        f4v accO[2] = {};
#pragma unroll
        for (int reg = 0; reg < 4; reg++) {
            pw[(lq * 4 + reg) * 40 + lr]      = f2b(p[0][reg]);
            pw[(lq * 4 + reg) * 40 + 16 + lr] = f2b(p[1][reg]);
        }
        {
            s8v ap0 = *(const s8v*)&pw[lr * 40 + lq * 8];
#pragma unroll
            for (int n = 0; n < 2; n++) {
                int d = 32 * h + 16 * n + lr;
                s8v bvf = *(const s8v*)&vt[SWZ(d, d * 64 + lq * 8)];
                accO[n] = mfma16(ap0, bvf, accO[n]);
            }
        }
#pragma unroll
        for (int reg = 0; reg < 4; reg++) {
            pw[(lq * 4 + reg) * 40 + lr]      = f2b(p[2][reg]);
            pw[(lq * 4 + reg) * 40 + 16 + lr] = f2b(p[3][reg]);
        }
        {
            s8v ap1 = *(const s8v*)&pw[lr * 40 + lq * 8];
#pragma unroll
            for (int n = 0; n < 2; n++) {
                int d = 32 * h + 16 * n + lr;
                s8v bvf = *(const s8v*)&vt[SWZ(d, d * 64 + 32 + lq * 8)];
                accO[n] = mfma16(ap1, bvf, accO[n]);
            }
        }
        // O transpose via scratch; accumulate proj
#pragma unroll
        for (int n = 0; n < 2; n++)
#pragma unroll
            for (int reg = 0; reg < 4; reg++)
                pw[(lq * 4 + reg) * 40 + 16 * n + lr] = f2b(accO[n][reg]);
        s8v apj = *(const s8v*)&pw[lr * 40 + lq * 8];
#pragma unroll
        for (int n = 0; n < 12; n++) {
            s8v bpj = *(const s8v*)&Wproj[(size_t)(16 * n + lr) * 192 + 32 * h + lq * 8];
            acc2[n] = mfma16(apj, bpj, acc2[n]);
        }
    }

    // ---- epilogue: x2 = proj + bias + x (roll(+4) scatter); fused LN2 ----
    float bpv[12], g2v[12], b2v[12];
#pragma unroll
    for (int n = 0; n < 12; n++) {
        int col = 16 * n + lr;
        bpv[n] = bproj[col]; g2v[n] = g2[col]; b2v[n] = bn2[col];
    }
#pragma unroll
    for (int reg = 0; reg < 4; reg++) {
        int tk = 16 * wv + lq * 4 + reg;
        int gh = (wh * 8 + (tk >> 3) + 4) & 127;
        int gw = (ww * 8 + (tk & 7) + 4) & 127;
        size_t base = (((size_t)bb * 128 + gh) * 128 + gw) * 192;
        float vv[12];
        float s = 0.f, sq = 0.f;
#pragma unroll
        for (int n = 0; n < 12; n++) {
            float v = acc2[n][reg] + bpv[n] + x[base + 16 * n + lr];
            vv[n] = v; s += v; sq += v * v;
        }
        s += __shfl_xor(s, 1); sq += __shfl_xor(sq, 1);
        s += __shfl_xor(s, 2); sq += __shfl_xor(sq, 2);
        s += __shfl_xor(s, 4); sq += __shfl_xor(sq, 4);
        s += __shfl_xor(s, 8); sq += __shfl_xor(sq, 8);
        float mean = s * (1.0f / 192.0f);
        float var = sq * (1.0f / 192.0f) - mean * mean;
        float rstd = 1.0f / sqrtf(var + 1e-5f);
#pragma unroll
        for (int n = 0; n < 12; n++) {
            size_t idx = base + 16 * n + lr;
            x2[idx]  = f2b(vv[n]);
            xln[idx] = f2b((vv[n] - mean) * rstd * g2v[n] + b2v[n]);
        }
    }
}

// =============== K2a: mh = gelu(xln @ W1^T + b1) =============================
// 128x128 tile, 4 waves x (64x64), K=192, LDT=40 pad (bank-conflict-free).
__global__ __launch_bounds__(256) void gemm_gelu(
    const u16* __restrict__ A,      // xln, ld 192
    const u16* __restrict__ W,      // W1 768x192 bf16
    const float* __restrict__ B1,
    u16* __restrict__ C)            // mh, ld 768
{
    __shared__ __align__(16) u16 As[128 * 40];   // 10240 B
    __shared__ __align__(16) u16 Bs[128 * 40];   // 10240 B
    const int tid = threadIdx.x;
    const int wv = tid >> 6, lane = tid & 63;
    const int lr = lane & 15, lq = lane >> 4;
    const int wm = (wv >> 1) * 64, wn = (wv & 1) * 64;
    const size_t m0 = (size_t)blockIdx.y * 128;
    const int n0 = blockIdx.x * 128;

    const int ar = tid >> 1, ac = (tid & 1) * 16;
    const u16* aptr = A + (m0 + ar) * 192 + ac;
    const u16* bptr = W + (size_t)(n0 + ar) * 192 + ac;

    f4v acc[4][4] = {};
    for (int k0 = 0; k0 < 192; k0 += 32) {
        __syncthreads();
        *(s8v*)&As[ar * 40 + ac]     = *(const s8v*)(aptr + k0);
        *(s8v*)&As[ar * 40 + ac + 8] = *(const s8v*)(aptr + k0 + 8);
        *(s8v*)&Bs[ar * 40 + ac]     = *(const s8v*)(bptr + k0);
        *(s8v*)&Bs[ar * 40 + ac + 8] = *(const s8v*)(bptr + k0 + 8);
        __syncthreads();
        s8v af[4], bf[4];
#pragma unroll
        for (int mt = 0; mt < 4; mt++)
            af[mt] = *(const s8v*)&As[(wm + 16 * mt + lr) * 40 + lq * 8];
#pragma unroll
        for (int nt = 0; nt < 4; nt++)
            bf[nt] = *(const s8v*)&Bs[(wn + 16 * nt + lr) * 40 + lq * 8];
#pragma unroll
        for (int mt = 0; mt < 4; mt++)
#pragma unroll
            for (int nt = 0; nt < 4; nt++)
                acc[mt][nt] = mfma16(af[mt], bf[nt], acc[mt][nt]);
    }

#pragma unroll
    for (int nt = 0; nt < 4; nt++) {
        int col = n0 + wn + 16 * nt + lr;
        float bb = B1[col];
#pragma unroll
        for (int mt = 0; mt < 4; mt++)
#pragma unroll
            for (int reg = 0; reg < 4; reg++) {
                size_t row = m0 + wm + 16 * mt + lq * 4 + reg;
                C[row * 768 + col] = f2b(gelu_f(acc[mt][nt][reg] + bb));
            }
    }
}

// =============== K2b: out = mh @ W2^T + b2 + x2 ==============================
// 256x64 tile, 4 waves x (64x64) sharing the Bs tile; K=768.
__global__ __launch_bounds__(256) void gemm_out(
    const u16* __restrict__ A,       // mh, ld 768
    const u16* __restrict__ W,       // W2 192x768 bf16
    const float* __restrict__ B2,
    const u16* __restrict__ resid,   // x2 bf16, ld 192
    float* __restrict__ Cout)        // ld 192
{
    __shared__ __align__(16) u16 As[256 * 40];   // 20480 B
    __shared__ __align__(16) u16 Bs[64 * 40];    //  5120 B
    const int tid = threadIdx.x;
    const int wv = tid >> 6, lane = tid & 63;
    const int lr = lane & 15, lq = lane >> 4;
    const int wm = wv * 64;
    const size_t m0 = (size_t)blockIdx.y * 256;
    const int n0 = blockIdx.x * 64;

    const u16* aptr = A + (m0 + tid) * 768;
    const int br = tid >> 2, bc = (tid & 3) * 8;
    const u16* bptr = W + (size_t)(n0 + br) * 768 + bc;

    f4v acc[4][4] = {};
    for (int k0 = 0; k0 < 768; k0 += 32) {
        __syncthreads();
#pragma unroll
        for (int i = 0; i < 4; i++)
            *(s8v*)&As[tid * 40 + i * 8] = *(const s8v*)(aptr + k0 + i * 8);
        *(s8v*)&Bs[br * 40 + bc] = *(const s8v*)(bptr + k0);
        __syncthreads();
        s8v af[4], bf[4];
#pragma unroll
        for (int mt = 0; mt < 4; mt++)
            af[mt] = *(const s8v*)&As[(wm + 16 * mt + lr) * 40 + lq * 8];
#pragma unroll
        for (int nt = 0; nt < 4; nt++)
            bf[nt] = *(const s8v*)&Bs[(16 * nt + lr) * 40 + lq * 8];
#pragma unroll
        for (int mt = 0; mt < 4; mt++)
#pragma unroll
            for (int nt = 0; nt < 4; nt++)
                acc[mt][nt] = mfma16(af[mt], bf[nt], acc[mt][nt]);
    }

#pragma unroll
    for (int nt = 0; nt < 4; nt++) {
        int col = n0 + 16 * nt + lr;
        float bb = B2[col];
#pragma unroll
        for (int mt = 0; mt < 4; mt++)
#pragma unroll
            for (int reg = 0; reg < 4; reg++) {
                size_t row = m0 + wm + 16 * mt + lq * 4 + reg;
                Cout[row * 192 + col] = acc[mt][nt][reg] + bb
                                      + b2f(resid[row * 192 + col]);
            }
    }
}

// ---------------- driver -----------------------------------------------------
extern "C" void kernel_launch(void* const* d_in, const int* in_sizes, int n_in,
                              void* d_out, int out_size, void* d_ws, size_t ws_size,
                              hipStream_t stream) {
    const float* x      = (const float*)d_in[0];
    const float* qkv_w  = (const float*)d_in[1];
    const float* qkv_b  = (const float*)d_in[2];
    const float* proj_w = (const float*)d_in[3];
    const float* proj_b = (const float*)d_in[4];
    const float* n1_g   = (const float*)d_in[5];
    const float* n1_b   = (const float*)d_in[6];
    const float* n2_g   = (const float*)d_in[7];
    const float* n2_b   = (const float*)d_in[8];
    const float* w1     = (const float*)d_in[9];
    const float* b1     = (const float*)d_in[10];
    const float* w2     = (const float*)d_in[11];
    const float* b2     = (const float*)d_in[12];
    float* out = (float*)d_out;

    u16* wsu = (u16*)d_ws;
    u16* wQ  = wsu;
    u16* wP  = wsu + OFF_PROJ;
    u16* wW1 = wsu + OFF_W1;
    u16* wW2 = wsu + OFF_W2;
    char* dataBase = (char*)d_ws + (1 << 20);
    size_t avail = (ws_size > (1 << 20)) ? ws_size - (1 << 20) : 0;

    dim3 blk(256);
    cvt_weights<<<W_TOTAL / 1024, blk, 0, stream>>>(qkv_w, proj_w, w1, w2, wsu);

    // Bs=4 keeps the mh slice (~100MB) L3-resident between K2a and K2b.
    const size_t perTok = (size_t)(192 + 192 + 768) * 2;   // x2, xln, mh (bf16)
    int Bs = 4;
    while (Bs > 1 && (size_t)Bs * 16384 * perTok > avail) Bs >>= 1;
    const int nslice = 16 / Bs;
    const size_t stok = (size_t)Bs * 16384;
    u16* x2buf  = (u16*)dataBase;
    u16* xlnbuf = x2buf + stok * 192;
    u16* mhbuf  = xlnbuf + stok * 192;

    for (int s = 0; s < nslice; s++) {
        const float* xs = x + (size_t)s * stok * 192;
        float* outs = out + (size_t)s * stok * 192;
        attn_fused<<<Bs * 256, blk, 0, stream>>>(xs, wQ, qkv_b, wP, proj_b,
                                                 n1_g, n1_b, n2_g, n2_b,
                                                 x2buf, xlnbuf);
        gemm_gelu<<<dim3(6, Bs * 128), blk, 0, stream>>>(xlnbuf, wW1, b1, mhbuf);
        gemm_out<<<dim3(3, Bs * 64), blk, 0, stream>>>(mhbuf, wW2, b2,
                                                       x2buf, outs);
    }
}

// Round 5
// 1477.897 us; speedup vs baseline: 1.7207x; 1.0366x over previous
//
#include <hip/hip_runtime.h>

// Swin block, MI355X gfx950. Global I/O fp32 (per reference); internal GEMMs
// bf16 via v_mfma_f32_16x16x32_bf16 with fp32 accumulation.
// Pipeline per batch-slice (Bs=4 so mh slice ~100MB stays L3-resident):
//   K0 cvt_weights : qkv_w/proj_w/w1/w2 fp32 -> bf16 in ws (once per call)
//   K1 attn_fused  : x -> x2 = x + proj(attn(LN1(x))), xln = LN2(x2)
//                    [37.9 KB LDS + <=128 VGPR -> 4 blocks/CU; hs persistent,
//                     per-head kb/vb; 12 barriers]
//   K2a gemm_gelu  : mh = gelu(xln @ w1^T + b1)  [128x128, global_load_lds]
//   K2b gemm_out   : out = mh @ w2^T + b2 + x2   [256x64,  global_load_lds]

typedef short s8v __attribute__((ext_vector_type(8)));
typedef float f4v __attribute__((ext_vector_type(4)));
typedef unsigned short u16;

static __device__ __forceinline__ float b2f(u16 u) {
    unsigned int x = ((unsigned int)u) << 16;
    return __builtin_bit_cast(float, x);
}
static __device__ __forceinline__ u16 f2b(float f) {
    unsigned int u = __builtin_bit_cast(unsigned int, f);
    u = (u + 0x7FFF + ((u >> 16) & 1)) >> 16;   // RNE
    return (u16)u;
}
static __device__ __forceinline__ f4v mfma16(s8v a, s8v b, f4v c) {
    return __builtin_amdgcn_mfma_f32_16x16x32_bf16(a, b, c, 0, 0, 0);
}

// direct global->LDS 16B DMA; LDS base must be wave-uniform (lane i lands at
// base + 16*i), global address is per-lane.
static __device__ __forceinline__ void gload16(const u16* g, u16* l) {
    __builtin_amdgcn_global_load_lds(
        (const __attribute__((address_space(1))) unsigned int*)g,
        (__attribute__((address_space(3))) unsigned int*)l, 16, 0, 0);
}

// Inline gelu (erf via Abramowitz-Stegun 7.1.26, |err|<1.5e-7). No libm call.
static __device__ __forceinline__ float gelu_f(float v) {
    float z = v * 0.70710678118654752f;
    float az = fabsf(z);
    float t = 1.0f / (1.0f + 0.3275911f * az);
    float poly = t * (0.254829592f + t * (-0.284496736f + t * (1.421413741f
               + t * (-1.453152027f + t * 1.061405429f))));
    float erfv = 1.0f - poly * __expf(-az * az);
    erfv = __builtin_copysignf(erfv, z);
    return 0.5f * v * (1.0f + erfv);
}

// XOR swizzle (attn LDS tiles): flip elem bits 3..5 with (row&7).
#define SWZ(r, e) ((e) ^ (((r) & 7) << 3))

// sizes (elems) of the 4 weight matrices and their bf16 ws offsets
#define SZ_QKV  110592   // 576 x 192
#define SZ_PROJ  36864   // 192 x 192
#define SZ_W1   147456   // 768 x 192
#define SZ_W2   147456   // 192 x 768
#define OFF_PROJ (SZ_QKV)
#define OFF_W1   (SZ_QKV + SZ_PROJ)
#define OFF_W2   (SZ_QKV + SZ_PROJ + SZ_W1)
#define W_TOTAL  (SZ_QKV + SZ_PROJ + SZ_W1 + SZ_W2)   // 442368

// =============== K0: weight fp32 -> bf16 =====================================
__global__ __launch_bounds__(256) void cvt_weights(
    const float* __restrict__ qkv_w, const float* __restrict__ proj_w,
    const float* __restrict__ w1, const float* __restrict__ w2,
    u16* __restrict__ dst)
{
    int i4 = (blockIdx.x * 256 + threadIdx.x) * 4;
    const float* src; int off;
    if (i4 < OFF_PROJ)     { src = qkv_w; off = i4; }
    else if (i4 < OFF_W1)  { src = proj_w; off = i4 - OFF_PROJ; }
    else if (i4 < OFF_W2)  { src = w1; off = i4 - OFF_W1; }
    else                   { src = w2; off = i4 - OFF_W2; }
    float4 v = *(const float4*)(src + off);
    ushort4 o;
    o.x = f2b(v.x); o.y = f2b(v.y); o.z = f2b(v.z); o.w = f2b(v.w);
    *(ushort4*)(dst + i4) = o;
}

// ---- attn helpers -----------------------------------------------------------
// QKV mini-GEMM for head h: 64 tokens x [q32|k32|v32], K=192. A-frags loaded
// per-k from persistent hs (keeps register pressure low). Writes l2norm'd
// k -> kb [64][32] swz, v -> vb [32][64] swz, q -> pw scratch -> aqOut.
static __device__ __forceinline__ void qkv_head(
    int h, const u16* hs, const u16* __restrict__ Wqkv,
    const float* __restrict__ bqkv, u16* kb, u16* vb, u16* pw,
    s8v& aqOut, int wv, int lr, int lq)
{
    const int trow = 16 * wv + lr;
    f4v acc[6] = {};
#pragma unroll
    for (int k = 0; k < 6; k++) {
        s8v af = *(const s8v*)&hs[SWZ(trow, trow * 192 + 32 * k + lq * 8)];
#pragma unroll
        for (int n = 0; n < 6; n++) {
            int wr = (n < 2) ? (32 * h + 16 * n + lr)
                   : (n < 4) ? (192 + 32 * h + 16 * (n - 2) + lr)
                             : (384 + 32 * h + 16 * (n - 4) + lr);
            s8v bf = *(const s8v*)&Wqkv[(size_t)wr * 192 + 32 * k + lq * 8];
            acc[n] = mfma16(af, bf, acc[n]);
        }
    }
    float bq0 = bqkv[32 * h + lr],       bq1 = bqkv[32 * h + 16 + lr];
    float bk0 = bqkv[192 + 32 * h + lr], bk1 = bqkv[192 + 32 * h + 16 + lr];
    float bv0 = bqkv[384 + 32 * h + lr], bv1 = bqkv[384 + 32 * h + 16 + lr];
#pragma unroll
    for (int reg = 0; reg < 4; reg++) {
        int row = 16 * wv + lq * 4 + reg;
        float q0 = acc[0][reg] + bq0, q1 = acc[1][reg] + bq1;
        float ss = q0 * q0 + q1 * q1;
#pragma unroll
        for (int m = 1; m < 16; m <<= 1) ss += __shfl_xor(ss, m);
        float inv = 1.0f / fmaxf(sqrtf(ss), 1e-12f);
        pw[(lq * 4 + reg) * 40 + lr]      = f2b(q0 * inv);
        pw[(lq * 4 + reg) * 40 + 16 + lr] = f2b(q1 * inv);

        float k0v = acc[2][reg] + bk0, k1v = acc[3][reg] + bk1;
        ss = k0v * k0v + k1v * k1v;
#pragma unroll
        for (int m = 1; m < 16; m <<= 1) ss += __shfl_xor(ss, m);
        inv = 1.0f / fmaxf(sqrtf(ss), 1e-12f);
        kb[SWZ(row, row * 32 + lr)]      = f2b(k0v * inv);
        kb[SWZ(row, row * 32 + 16 + lr)] = f2b(k1v * inv);

        vb[SWZ(lr, lr * 64 + row)]             = f2b(acc[4][reg] + bv0);
        vb[SWZ(16 + lr, (16 + lr) * 64 + row)] = f2b(acc[5][reg] + bv1);
    }
    aqOut = *(const s8v*)&pw[lr * 40 + lq * 8];
}

// S = q k^T -> softmax/clip -> O = P V -> accumulate proj into acc2.
static __device__ __forceinline__ void attn_head(
    int h, s8v aq, const u16* kb, const u16* vb, u16* pw,
    f4v* acc2, const u16* __restrict__ Wproj, int wv, int lr, int lq)
{
    f4v accS[4] = {};
#pragma unroll
    for (int j = 0; j < 4; j++) {
        int kr = 16 * j + lr;
        s8v bk = *(const s8v*)&kb[SWZ(kr, kr * 32 + lq * 8)];
        accS[j] = mfma16(aq, bk, accS[j]);
    }
    const float scale = 0.17677669529663687f;   // 32^-0.5
    float p[4][4];
#pragma unroll
    for (int reg = 0; reg < 4; reg++) {
        float v0 = accS[0][reg] * scale, v1 = accS[1][reg] * scale;
        float v2 = accS[2][reg] * scale, v3 = accS[3][reg] * scale;
        float mx = fmaxf(fmaxf(v0, v1), fmaxf(v2, v3));
#pragma unroll
        for (int m = 1; m < 16; m <<= 1) mx = fmaxf(mx, __shfl_xor(mx, m));
        float e0 = __expf(v0 - mx), e1 = __expf(v1 - mx);
        float e2 = __expf(v2 - mx), e3 = __expf(v3 - mx);
        float sum = e0 + e1 + e2 + e3;
#pragma unroll
        for (int m = 1; m < 16; m <<= 1) sum += __shfl_xor(sum, m);
        float is = 1.0f / sum;
        p[0][reg] = fminf(fmaxf(e0 * is, 1e-6f), 1.0f);
        p[1][reg] = fminf(fmaxf(e1 * is, 1e-6f), 1.0f);
        p[2][reg] = fminf(fmaxf(e2 * is, 1e-6f), 1.0f);
        p[3][reg] = fminf(fmaxf(e3 * is, 1e-6f), 1.0f);
    }
    f4v accO[2] = {};
#pragma unroll
    for (int reg = 0; reg < 4; reg++) {
        pw[(lq * 4 + reg) * 40 + lr]      = f2b(p[0][reg]);
        pw[(lq * 4 + reg) * 40 + 16 + lr] = f2b(p[1][reg]);
    }
    {
        s8v ap = *(const s8v*)&pw[lr * 40 + lq * 8];
#pragma unroll
        for (int n = 0; n < 2; n++) {
            int d = 16 * n + lr;
            s8v bvf = *(const s8v*)&vb[SWZ(d, d * 64 + lq * 8)];
            accO[n] = mfma16(ap, bvf, accO[n]);
        }
    }
#pragma unroll
    for (int reg = 0; reg < 4; reg++) {
        pw[(lq * 4 + reg) * 40 + lr]      = f2b(p[2][reg]);
        pw[(lq * 4 + reg) * 40 + 16 + lr] = f2b(p[3][reg]);
    }
    {
        s8v ap = *(const s8v*)&pw[lr * 40 + lq * 8];
#pragma unroll
        for (int n = 0; n < 2; n++) {
            int d = 16 * n + lr;
            s8v bvf = *(const s8v*)&vb[SWZ(d, d * 64 + 32 + lq * 8)];
            accO[n] = mfma16(ap, bvf, accO[n]);
        }
    }
    // O transpose via scratch; accumulate proj
#pragma unroll
    for (int n = 0; n < 2; n++)
#pragma unroll
        for (int reg = 0; reg < 4; reg++)
            pw[(lq * 4 + reg) * 40 + 16 * n + lr] = f2b(accO[n][reg]);
    s8v apj = *(const s8v*)&pw[lr * 40 + lq * 8];
#pragma unroll
    for (int n = 0; n < 12; n++) {
        s8v bpj = *(const s8v*)&Wproj[(size_t)(16 * n + lr) * 192 + 32 * h + lq * 8];
        acc2[n] = mfma16(apj, bpj, acc2[n]);
    }
}

// =============== K1: fused LN1 + QKV + window-attention + proj + resid + LN2 =
// LDS (elems): hs [0,12288) 64x192 swz, persistent all kernel (wave-local rows)
//              kb [12288,14336) 64x32 swz | vb [14336,16384) 32x64 swz
//              pscr [16384,18944) 4 waves x 640
// Total 37,888 B -> 4 blocks/CU (LDS); <=128 VGPR -> 4 blocks (VGPR). 50% occ.
__global__ __launch_bounds__(256, 4) void attn_fused(
    const float* __restrict__ x, const u16* __restrict__ Wqkv,
    const float* __restrict__ bqkv, const u16* __restrict__ Wproj,
    const float* __restrict__ bproj, const float* __restrict__ g1,
    const float* __restrict__ bn1, const float* __restrict__ g2,
    const float* __restrict__ bn2, u16* __restrict__ x2,
    u16* __restrict__ xln)
{
    __shared__ __align__(16) u16 lds[18944];   // 37888 B
    u16* hs = lds;
    u16* kb = lds + 12288;
    u16* vb = lds + 14336;
    u16* pscr = lds + 16384;

    const int tid = threadIdx.x;
    const int wv = tid >> 6, lane = tid & 63;
    const int lr = lane & 15, lq = lane >> 4;
    const int wloc = blockIdx.x;
    const int bb = wloc >> 8, wh = (wloc >> 4) & 15, ww = wloc & 15;
    u16* pw = pscr + wv * 640;

    // ---- LN1 stage (single pass; x kept in registers; wave-local rows) ----
    {
        int tk = tid >> 2, q4 = tid & 3;
        int gh = (wh * 8 + (tk >> 3) + 4) & 127;
        int gw = (ww * 8 + (tk & 7) + 4) & 127;
        const float* xr = x + (((size_t)bb * 128 + gh) * 128 + gw) * 192 + q4 * 48;
        float4 xv[12];
        float s = 0.f, sq = 0.f;
#pragma unroll
        for (int i = 0; i < 12; i++) {
            xv[i] = *(const float4*)(xr + i * 4);
            s += xv[i].x + xv[i].y + xv[i].z + xv[i].w;
            sq += xv[i].x * xv[i].x + xv[i].y * xv[i].y
                + xv[i].z * xv[i].z + xv[i].w * xv[i].w;
        }
        s += __shfl_xor(s, 1); sq += __shfl_xor(sq, 1);
        s += __shfl_xor(s, 2); sq += __shfl_xor(sq, 2);
        float mean = s * (1.0f / 192.0f);
        float var = sq * (1.0f / 192.0f) - mean * mean;
        float rstd = 1.0f / sqrtf(var + 1e-5f);
#pragma unroll
        for (int i = 0; i < 12; i += 2) {
            int c0 = q4 * 48 + i * 4;
            float4 ga  = *(const float4*)(g1 + c0);
            float4 gb  = *(const float4*)(g1 + c0 + 4);
            float4 ba  = *(const float4*)(bn1 + c0);
            float4 bbv = *(const float4*)(bn1 + c0 + 4);
            s8v ov;
            ov[0] = (short)f2b((xv[i].x - mean) * rstd * ga.x + ba.x);
            ov[1] = (short)f2b((xv[i].y - mean) * rstd * ga.y + ba.y);
            ov[2] = (short)f2b((xv[i].z - mean) * rstd * ga.z + ba.z);
            ov[3] = (short)f2b((xv[i].w - mean) * rstd * ga.w + ba.w);
            ov[4] = (short)f2b((xv[i + 1].x - mean) * rstd * gb.x + bbv.x);
            ov[5] = (short)f2b((xv[i + 1].y - mean) * rstd * gb.y + bbv.y);
            ov[6] = (short)f2b((xv[i + 1].z - mean) * rstd * gb.z + bbv.z);
            ov[7] = (short)f2b((xv[i + 1].w - mean) * rstd * gb.w + bbv.w);
            *(s8v*)&hs[SWZ(tk, tk * 192 + c0)] = ov;
        }
    }
    // no barrier needed: hs rows are wave-local for both write and read

    // ---- per-head: QKV -> publish kb/vb -> attn; 2 barriers/head ----
    f4v acc2[12] = {};
#pragma unroll 1
    for (int h = 0; h < 6; h++) {
        s8v aq;
        qkv_head(h, hs, Wqkv, bqkv, kb, vb, pw, aq, wv, lr, lq);
        __syncthreads();             // kb/vb published to all waves
        attn_head(h, aq, kb, vb, pw, acc2, Wproj, wv, lr, lq);
        __syncthreads();             // all readers done before next overwrite
    }

    // ---- epilogue: x2 = proj + bias + x (roll(+4) scatter); fused LN2 ----
    float bpv[12], g2v[12], b2v[12];
#pragma unroll
    for (int n = 0; n < 12; n++) {
        int col = 16 * n + lr;
        bpv[n] = bproj[col]; g2v[n] = g2[col]; b2v[n] = bn2[col];
    }
#pragma unroll
    for (int reg = 0; reg < 4; reg++) {
        int tk = 16 * wv + lq * 4 + reg;
        int gh = (wh * 8 + (tk >> 3) + 4) & 127;
        int gw = (ww * 8 + (tk & 7) + 4) & 127;
        size_t base = (((size_t)bb * 128 + gh) * 128 + gw) * 192;
        float vv[12];
        float s = 0.f, sq = 0.f;
#pragma unroll
        for (int n = 0; n < 12; n++) {
            float v = acc2[n][reg] + bpv[n] + x[base + 16 * n + lr];
            vv[n] = v; s += v; sq += v * v;
        }
        s += __shfl_xor(s, 1); sq += __shfl_xor(sq, 1);
        s += __shfl_xor(s, 2); sq += __shfl_xor(sq, 2);
        s += __shfl_xor(s, 4); sq += __shfl_xor(sq, 4);
        s += __shfl_xor(s, 8); sq += __shfl_xor(sq, 8);
        float mean = s * (1.0f / 192.0f);
        float var = sq * (1.0f / 192.0f) - mean * mean;
        float rstd = 1.0f / sqrtf(var + 1e-5f);
#pragma unroll
        for (int n = 0; n < 12; n++) {
            size_t idx = base + 16 * n + lr;
            x2[idx]  = f2b(vv[n]);
            xln[idx] = f2b((vv[n] - mean) * rstd * g2v[n] + b2v[n]);
        }
    }
}

// =============== K2a: mh = gelu(xln @ W1^T + b1) =============================
// 128x128 tile, 4 waves x (64x64), K=192. Staging via global_load_lds (16B),
// linear LDS [rows][32] with source-side chunk swizzle (chunk ^= row&3) and
// matching read-side XOR (4-way conflict max).
__global__ __launch_bounds__(256) void gemm_gelu(
    const u16* __restrict__ A,      // xln, ld 192
    const u16* __restrict__ W,      // W1 768x192 bf16
    const float* __restrict__ B1,
    u16* __restrict__ C)            // mh, ld 768
{
    __shared__ __align__(16) u16 As[128 * 32];   // 8192 B
    __shared__ __align__(16) u16 Bs[128 * 32];   // 8192 B
    const int tid = threadIdx.x;
    const int wv = tid >> 6, lane = tid & 63;
    const int lr = lane & 15, lq = lane >> 4;
    const int wm = (wv >> 1) * 64, wn = (wv & 1) * 64;
    const size_t m0 = (size_t)blockIdx.y * 128;
    const int n0 = blockIdx.x * 128;

    const int srow = lane >> 2;                        // 0..15
    const int sc8 = (((lane & 3) ^ (srow & 3)) << 3);  // swizzled src chunk
    const u16* aptr = A + (m0 + 32 * wv + srow) * 192 + sc8;
    const u16* bptr = W + (size_t)(n0 + 32 * wv + srow) * 192 + sc8;

    f4v acc[4][4] = {};
    for (int k0 = 0; k0 < 192; k0 += 32) {
        __syncthreads();
        gload16(aptr + k0,            &As[(32 * wv) * 32]);
        gload16(aptr + 16 * 192 + k0, &As[(32 * wv + 16) * 32]);
        gload16(bptr + k0,            &Bs[(32 * wv) * 32]);
        gload16(bptr + 16 * 192 + k0, &Bs[(32 * wv + 16) * 32]);
        __syncthreads();   // drains vmcnt -> LDS valid
        s8v af[4], bf[4];
#pragma unroll
        for (int mt = 0; mt < 4; mt++) {
            int r = wm + 16 * mt + lr;
            af[mt] = *(const s8v*)&As[r * 32 + ((lq ^ (r & 3)) << 3)];
        }
#pragma unroll
        for (int nt = 0; nt < 4; nt++) {
            int r = wn + 16 * nt + lr;
            bf[nt] = *(const s8v*)&Bs[r * 32 + ((lq ^ (r & 3)) << 3)];
        }
#pragma unroll
        for (int mt = 0; mt < 4; mt++)
#pragma unroll
            for (int nt = 0; nt < 4; nt++)
                acc[mt][nt] = mfma16(af[mt], bf[nt], acc[mt][nt]);
    }

#pragma unroll
    for (int nt = 0; nt < 4; nt++) {
        int col = n0 + wn + 16 * nt + lr;
        float bb = B1[col];
#pragma unroll
        for (int mt = 0; mt < 4; mt++)
#pragma unroll
            for (int reg = 0; reg < 4; reg++) {
                size_t row = m0 + wm + 16 * mt + lq * 4 + reg;
                C[row * 768 + col] = f2b(gelu_f(acc[mt][nt][reg] + bb));
            }
    }
}

// =============== K2b: out = mh @ W2^T + b2 + x2 ==============================
// 256x64 tile, 4 waves x (64x64) sharing Bs; K=768; global_load_lds staging.
__global__ __launch_bounds__(256) void gemm_out(
    const u16* __restrict__ A,       // mh, ld 768
    const u16* __restrict__ W,       // W2 192x768 bf16
    const float* __restrict__ B2,
    const u16* __restrict__ resid,   // x2 bf16, ld 192
    float* __restrict__ Cout)        // ld 192
{
    __shared__ __align__(16) u16 As[256 * 32];   // 16384 B
    __shared__ __align__(16) u16 Bs[64 * 32];    //  4096 B
    const int tid = threadIdx.x;
    const int wv = tid >> 6, lane = tid & 63;
    const int lr = lane & 15, lq = lane >> 4;
    const int wm = wv * 64;
    const size_t m0 = (size_t)blockIdx.y * 256;
    const int n0 = blockIdx.x * 64;

    const int srow = lane >> 2;
    const int sc8 = (((lane & 3) ^ (srow & 3)) << 3);
    const u16* aptr = A + (m0 + 64 * wv + srow) * 768 + sc8;
    const u16* bptr = W + (size_t)(n0 + 16 * wv + srow) * 768 + sc8;

    f4v acc[4][4] = {};
    for (int k0 = 0; k0 < 768; k0 += 32) {
        __syncthreads();
#pragma unroll
        for (int j = 0; j < 4; j++)
            gload16(aptr + (size_t)(16 * j) * 768 + k0,
                    &As[(64 * wv + 16 * j) * 32]);
        gload16(bptr + k0, &Bs[(16 * wv) * 32]);
        __syncthreads();
        s8v af[4], bf[4];
#pragma unroll
        for (int mt = 0; mt < 4; mt++) {
            int r = wm + 16 * mt + lr;
            af[mt] = *(const s8v*)&As[r * 32 + ((lq ^ (r & 3)) << 3)];
        }
#pragma unroll
        for (int nt = 0; nt < 4; nt++) {
            int r = 16 * nt + lr;
            bf[nt] = *(const s8v*)&Bs[r * 32 + ((lq ^ (r & 3)) << 3)];
        }
#pragma unroll
        for (int mt = 0; mt < 4; mt++)
#pragma unroll
            for (int nt = 0; nt < 4; nt++)
                acc[mt][nt] = mfma16(af[mt], bf[nt], acc[mt][nt]);
    }

#pragma unroll
    for (int nt = 0; nt < 4; nt++) {
        int col = n0 + 16 * nt + lr;
        float bb = B2[col];
#pragma unroll
        for (int mt = 0; mt < 4; mt++)
#pragma unroll
            for (int reg = 0; reg < 4; reg++) {
                size_t row = m0 + wm + 16 * mt + lq * 4 + reg;
                Cout[row * 192 + col] = acc[mt][nt][reg] + bb
                                      + b2f(resid[row * 192 + col]);
            }
    }
}

// ---------------- driver -----------------------------------------------------
extern "C" void kernel_launch(void* const* d_in, const int* in_sizes, int n_in,
                              void* d_out, int out_size, void* d_ws, size_t ws_size,
                              hipStream_t stream) {
    const float* x      = (const float*)d_in[0];
    const float* qkv_w  = (const float*)d_in[1];
    const float* qkv_b  = (const float*)d_in[2];
    const float* proj_w = (const float*)d_in[3];
    const float* proj_b = (const float*)d_in[4];
    const float* n1_g   = (const float*)d_in[5];
    const float* n1_b   = (const float*)d_in[6];
    const float* n2_g   = (const float*)d_in[7];
    const float* n2_b   = (const float*)d_in[8];
    const float* w1     = (const float*)d_in[9];
    const float* b1     = (const float*)d_in[10];
    const float* w2     = (const float*)d_in[11];
    const float* b2     = (const float*)d_in[12];
    float* out = (float*)d_out;

    u16* wsu = (u16*)d_ws;
    u16* wQ  = wsu;
    u16* wP  = wsu + OFF_PROJ;
    u16* wW1 = wsu + OFF_W1;
    u16* wW2 = wsu + OFF_W2;
    char* dataBase = (char*)d_ws + (1 << 20);
    size_t avail = (ws_size > (1 << 20)) ? ws_size - (1 << 20) : 0;

    dim3 blk(256);
    cvt_weights<<<W_TOTAL / 1024, blk, 0, stream>>>(qkv_w, proj_w, w1, w2, wsu);

    // Bs=4 keeps the mh slice (~100MB) L3-resident between K2a and K2b.
    const size_t perTok = (size_t)(192 + 192 + 768) * 2;   // x2, xln, mh (bf16)
    int Bs = 4;
    while (Bs > 1 && (size_t)Bs * 16384 * perTok > avail) Bs >>= 1;
    const int nslice = 16 / Bs;
    const size_t stok = (size_t)Bs * 16384;
    u16* x2buf  = (u16*)dataBase;
    u16* xlnbuf = x2buf + stok * 192;
    u16* mhbuf  = xlnbuf + stok * 192;

    for (int s = 0; s < nslice; s++) {
        const float* xs = x + (size_t)s * stok * 192;
        float* outs = out + (size_t)s * stok * 192;
        attn_fused<<<Bs * 256, blk, 0, stream>>>(xs, wQ, qkv_b, wP, proj_b,
                                                 n1_g, n1_b, n2_g, n2_b,
                                                 x2buf, xlnbuf);
        gemm_gelu<<<dim3(6, Bs * 128), blk, 0, stream>>>(xlnbuf, wW1, b1, mhbuf);
        gemm_out<<<dim3(3, Bs * 64), blk, 0, stream>>>(mhbuf, wW2, b2,
                                                       x2buf, outs);
    }
}